// Round 7
// baseline (250.395 us; speedup 1.0000x reference)
//
#include <hip/hip_runtime.h>
#include <hip/hip_bf16.h>

// PolyAttentionBlock: B=16 N=1024 C=768 H=12 D=64. attn = a*s^2+b*s+c (no softmax).
// cvt -> QKV GEMM (m97 128x128, BK=64, k-major chunk LDS; Q->qh K->kh V->vT) -> attn -> proj.

typedef float  f32x4  __attribute__((ext_vector_type(4)));
typedef __bf16 bf16x8 __attribute__((ext_vector_type(8)));
typedef __bf16 bf16x4 __attribute__((ext_vector_type(4)));

#define AS1 __attribute__((address_space(1)))
#define AS3 __attribute__((address_space(3)))

__device__ __forceinline__ void gl16(const void* g, void* l) {
  __builtin_amdgcn_global_load_lds((const AS1 unsigned int*)g, (AS3 unsigned int*)l, 16, 0, 0);
}

// ---------------- f32 -> bf16 cast ----------------
__global__ __launch_bounds__(256) void cvtk(const float* __restrict__ s,
                                            __bf16* __restrict__ d, int n) {
  int i = (blockIdx.x * 256 + threadIdx.x) * 4;
  if (i >= n) return;
  float4 v = *reinterpret_cast<const float4*>(s + i);
  bf16x4 o = { (__bf16)v.x, (__bf16)v.y, (__bf16)v.z, (__bf16)v.w };
  *reinterpret_cast<bf16x4*>(d + i) = o;
}

// ---------------- 128x128 BK=64 GEMM core (m97 structure) ----------------
// 256 thr = 4 waves (2x2 of 64x64). LDS 32KB single-buffered.
// LDS: per tile 16 chunks of 1KB; chunk c=(rowgrp<<1)|khalf holds rows rowgrp*16..+15,
// k = khalf*32 + lg*8 + e, layout [lg][l15][8elems] -> frag read is a contiguous 1KB
// wave read (0 bank conflicts); staged by gl16 with linear dest.
// acc[m][n][e]: SWAP -> C[row0+rw+m*16+l15][col0+cw+n*16+lg*4+e]  (e along cols)
//              !SWAP -> C[row0+rw+m*16+lg*4+e][col0+cw+n*16+l15]  (e along rows)
template <bool SWAP>
__device__ __forceinline__ void core128(const __bf16* __restrict__ A,
                                        const __bf16* __restrict__ W, int K,
                                        int row0, int col0, char* lds,
                                        int w, int l, f32x4 (&acc)[4][4]) {
  const int l15 = l & 15, lg = l >> 4;
  const int rw = (w >> 1) * 64, cw = (w & 1) * 64;
  const int NT = K >> 6;
  for (int t = 0; t < NT; ++t) {
    const int k0 = t * 64;
#pragma unroll
    for (int c4 = 0; c4 < 4; ++c4) {
      const int c = c4 * 4 + w;                       // chunk id
      const int r = row0 + ((c >> 1) << 4) + l15;     // rowgrp*16 + l15
      gl16(A + (size_t)r * K + k0 + (c & 1) * 32 + lg * 8, lds + c * 1024);
    }
#pragma unroll
    for (int c4 = 0; c4 < 4; ++c4) {
      const int c = c4 * 4 + w;
      const int r = col0 + ((c >> 1) << 4) + l15;
      gl16(W + (size_t)r * K + k0 + (c & 1) * 32 + lg * 8, lds + 16384 + c * 1024);
    }
    __syncthreads();  // drains vmcnt(0), then barrier
#pragma unroll
    for (int kk = 0; kk < 2; ++kk) {
      bf16x8 af[4], bfr[4];
#pragma unroll
      for (int m = 0; m < 4; ++m)
        af[m] = *(const bf16x8*)(lds + (((rw >> 4) + m) * 2 + kk) * 1024 + lg * 256 + l15 * 16);
#pragma unroll
      for (int n = 0; n < 4; ++n)
        bfr[n] = *(const bf16x8*)(lds + 16384 + (((cw >> 4) + n) * 2 + kk) * 1024 + lg * 256 + l15 * 16);
      __builtin_amdgcn_s_setprio(1);
#pragma unroll
      for (int m = 0; m < 4; ++m)
#pragma unroll
        for (int n = 0; n < 4; ++n) {
          if (SWAP)
            acc[m][n] = __builtin_amdgcn_mfma_f32_16x16x32_bf16(bfr[n], af[m], acc[m][n], 0, 0, 0);
          else
            acc[m][n] = __builtin_amdgcn_mfma_f32_16x16x32_bf16(af[m], bfr[n], acc[m][n], 0, 0, 0);
        }
      __builtin_amdgcn_s_setprio(0);
    }
    __syncthreads();  // protect LDS before next stage
  }
}

// MODE 0: QKV. col<768 -> qh[bh][n][64]; <1536 -> kh; else V -> vT[bh][64][1024].
// MODE 1: proj, f32 packed out.
template <int MODE>
__global__ __launch_bounds__(256) void gemmk(
    const __bf16* __restrict__ A, const __bf16* __restrict__ W,
    const float* __restrict__ bias, __bf16* __restrict__ qh,
    __bf16* __restrict__ kh, __bf16* __restrict__ vt,
    float* __restrict__ fout, int K, int nby, int chunk, int ldo) {
  __shared__ char lds[32768];
  const int t = threadIdx.x, w = t >> 6, l = t & 63;
  const int l15 = l & 15, lg = l >> 4;
  const int rw = (w >> 1) * 64, cw = (w & 1) * 64;

  // bijective XCD-chunked swizzle (grid % 8 == 0), row-major chunks
  const int fid = blockIdx.x;
  const int logical = (fid & 7) * chunk + (fid >> 3);
  const int bx = logical / nby, by = logical % nby;
  const int row0 = bx * 128, col0 = by * 128;

  const f32x4 zz = {0.f, 0.f, 0.f, 0.f};
  f32x4 acc[4][4];
#pragma unroll
  for (int m = 0; m < 4; ++m)
#pragma unroll
    for (int n = 0; n < 4; ++n) acc[m][n] = zz;

  const bool swap = (MODE == 1) || (col0 < 1536);
  if (swap) core128<true>(A, W, K, row0, col0, lds, w, l, acc);
  else      core128<false>(A, W, K, row0, col0, lds, w, l, acc);

  if (swap) {
    f32x4 bv4[4];
#pragma unroll
    for (int n = 0; n < 4; ++n)
      bv4[n] = *(const f32x4*)(bias + col0 + cw + n * 16 + lg * 4);
#pragma unroll
    for (int m = 0; m < 4; ++m) {
      const int row = row0 + rw + m * 16 + l15;
#pragma unroll
      for (int n = 0; n < 4; ++n) {
        const int colb = col0 + cw + n * 16 + lg * 4;
        if (MODE == 1) {
          f32x4 v;
#pragma unroll
          for (int e = 0; e < 4; ++e) v[e] = acc[m][n][e] + bv4[n][e];
          *(f32x4*)(fout + (size_t)row * ldo + colb) = v;
        } else {
          bf16x4 pk;
#pragma unroll
          for (int e = 0; e < 4; ++e) pk[e] = (__bf16)(acc[m][n][e] + bv4[n][e]);
          const int b = row >> 10, nn = row & 1023;
          if (colb < 768) {        // Q
            const int h = colb >> 6, d0 = colb & 63;
            *(bf16x4*)(qh + (((size_t)(b * 12 + h)) << 16) + nn * 64 + d0) = pk;
          } else {                 // K
            const int ck = colb - 768, h = ck >> 6, d0 = ck & 63;
            *(bf16x4*)(kh + (((size_t)(b * 12 + h)) << 16) + nn * 64 + d0) = pk;
          }
        }
      }
    }
  } else {
    // V path: e runs along token-rows -> contiguous nn in vT[bh][64][1024]
    float bv[4];
#pragma unroll
    for (int n = 0; n < 4; ++n) bv[n] = bias[col0 + cw + n * 16 + l15];
#pragma unroll
    for (int m = 0; m < 4; ++m)
#pragma unroll
      for (int n = 0; n < 4; ++n) {
        const int cv = col0 - 1536 + cw + n * 16 + l15;
        const int h = cv >> 6, d = cv & 63;
        const int row = row0 + rw + m * 16 + lg * 4;
        const int b = row >> 10, nn = row & 1023;
        bf16x4 pk;
#pragma unroll
        for (int e = 0; e < 4; ++e) pk[e] = (__bf16)(acc[m][n][e] + bv[n]);
        *(bf16x4*)(vt + (((size_t)(b * 12 + h)) << 16) + (d << 10) + nn) = pk;
      }
  }
}

// ---------------- fused poly attention ----------------
// grid 1536 (XCD-chunked), 256 thr = 4 waves; KVBLK=64, 16 tiles.
__global__ __launch_bounds__(256, 3) void attnk(const __bf16* __restrict__ qh,
                                                const __bf16* __restrict__ kh,
                                                const __bf16* __restrict__ vT,
                                                __bf16* __restrict__ o,
                                                const float* __restrict__ poly) {
  __shared__ __bf16 lK[64 * 64];   // 8KB  [m][d=64], 128B rows, XOR-swizzled
  __shared__ __bf16 lV[64 * 64];   // 8KB  [d][m=64], 128B rows, XOR-swizzled
  __shared__ __bf16 lP[128 * 64];  // 16KB [q][m=64]; wave w owns rows w*32..+31
  const int t = threadIdx.x, w = t >> 6, l = t & 63;
  const int l15 = l & 15, lg = l >> 4;

  const int fid = blockIdx.y * 8 + blockIdx.x;       // 0..1535
  const int logical = (fid & 7) * 192 + (fid >> 3);
  const int bh = logical >> 3, q0 = (logical & 7) * 128;
  const float pa = poly[0], pb = poly[1], pc = poly[2];
  const f32x4 zz = {0.f, 0.f, 0.f, 0.f};
  const size_t bhoff = ((size_t)bh) << 16;

  bf16x8 qf[2][2];
#pragma unroll
  for (int a = 0; a < 2; ++a)
#pragma unroll
    for (int kk = 0; kk < 2; ++kk)
      qf[a][kk] = *(const bf16x8*)(qh + bhoff + (q0 + w * 32 + 16 * a + l15) * 64 +
                                   kk * 32 + lg * 8);

  f32x4 oacc[2][4];
#pragma unroll
  for (int mf = 0; mf < 2; ++mf)
#pragma unroll
    for (int n = 0; n < 4; ++n) oacc[mf][n] = zz;

  const int srow = l >> 3;
  const int sunit = (l & 7) ^ (srow & 7);
  for (int mt = 0; mt < 16; ++mt) {
    const int m0 = mt * 64;
#pragma unroll
    for (int c = 0; c < 2; ++c) {
      int s = w * 2 + c;
      gl16(kh + bhoff + (m0 + 8 * s + srow) * 64 + (sunit << 3), (char*)lK + s * 1024);
    }
#pragma unroll
    for (int c = 0; c < 2; ++c) {
      int s = w * 2 + c;
      gl16(vT + bhoff + (8 * s + srow) * 1024 + m0 + (sunit << 3), (char*)lV + s * 1024);
    }
    __syncthreads();

    // S^T = K Q^T
    f32x4 sacc[2][4];
#pragma unroll
    for (int kk = 0; kk < 2; ++kk) {
      bf16x8 kf[4];
#pragma unroll
      for (int c = 0; c < 4; ++c) {
        int r = 16 * c + l15;
        kf[c] = *(const bf16x8*)((const char*)lK + r * 128 + (((kk * 4 + lg) ^ (r & 7)) << 4));
      }
      __builtin_amdgcn_s_setprio(1);
#pragma unroll
      for (int a = 0; a < 2; ++a)
#pragma unroll
        for (int c = 0; c < 4; ++c)
          sacc[a][c] = __builtin_amdgcn_mfma_f32_16x16x32_bf16(
              kf[c], qf[a][kk], kk == 0 ? zz : sacc[a][c], 0, 0, 0);
      __builtin_amdgcn_s_setprio(0);
    }

    // poly -> packed bf16x4 ds_write
#pragma unroll
    for (int a = 0; a < 2; ++a)
#pragma unroll
      for (int c = 0; c < 4; ++c) {
        int q = w * 32 + 16 * a + l15;
        int mb2 = 32 * c + 8 * lg;
        bf16x4 pk;
#pragma unroll
        for (int e = 0; e < 4; ++e) {
          float s = sacc[a][c][e] * 0.125f;
          float p = (pa * s + pb) * s + pc;
          pk[e] = (__bf16)p;
        }
        *(bf16x4*)((char*)lP + q * 128 + (mb2 ^ ((q & 7) << 4))) = pk;
      }

    // O += P @ V
#pragma unroll
    for (int kk = 0; kk < 2; ++kk) {
      bf16x8 vf[4];
#pragma unroll
      for (int nf = 0; nf < 4; ++nf) {
        int d = 16 * nf + l15;
        vf[nf] = *(const bf16x8*)((const char*)lV + d * 128 + (((kk * 4 + lg) ^ (d & 7)) << 4));
      }
      bf16x8 pf[2];
#pragma unroll
      for (int mf = 0; mf < 2; ++mf) {
        int q = w * 32 + 16 * mf + l15;
        pf[mf] = *(const bf16x8*)((const char*)lP + q * 128 + (((kk * 4 + lg) ^ (q & 7)) << 4));
      }
      __builtin_amdgcn_s_setprio(1);
#pragma unroll
      for (int mf = 0; mf < 2; ++mf)
#pragma unroll
        for (int nf = 0; nf < 4; ++nf)
          oacc[mf][nf] = __builtin_amdgcn_mfma_f32_16x16x32_bf16(pf[mf], vf[nf], oacc[mf][nf], 0, 0, 0);
      __builtin_amdgcn_s_setprio(0);
    }
    __syncthreads();
  }

  const int b = bh / 12, h = bh - b * 12;
#pragma unroll
  for (int mf = 0; mf < 2; ++mf)
#pragma unroll
    for (int nf = 0; nf < 4; ++nf)
#pragma unroll
      for (int e = 0; e < 4; ++e) {
        int row = q0 + w * 32 + 16 * mf + 4 * lg + e;
        int d = 16 * nf + l15;
        o[(size_t)(b * 1024 + row) * 768 + h * 64 + d] = (__bf16)oacc[mf][nf][e];
      }
}

// ---------------- launch ----------------
extern "C" void kernel_launch(void* const* d_in, const int* in_sizes, int n_in,
                              void* d_out, int out_size, void* d_ws, size_t ws_size,
                              hipStream_t stream) {
  const float* x      = (const float*)d_in[0];
  const float* w_qkv  = (const float*)d_in[1];
  const float* b_qkv  = (const float*)d_in[2];
  const float* w_proj = (const float*)d_in[3];
  const float* b_proj = (const float*)d_in[4];
  const float* poly   = (const float*)d_in[5];

  char* ws = (char*)d_ws;
  __bf16* xb     = (__bf16*)(ws);                 // 16384x768   = 25165824 B
  __bf16* wqkvb  = (__bf16*)(ws + 25165824);      // 2304x768    =  3538944 B
  __bf16* wprojb = (__bf16*)(ws + 28704768);      // 768x768     =  1179648 B
  __bf16* qh     = (__bf16*)(ws + 29884416);      // 192x1024x64 = 25165824 B
  __bf16* kh     = (__bf16*)(ws + 55050240);      // 192x1024x64 = 25165824 B
  __bf16* vtb    = (__bf16*)(ws + 80216064);      // 192x64x1024 = 25165824 B
  __bf16* ob     = (__bf16*)(ws + 105381888);     // 16384x768   = 25165824 B

  cvtk<<<12582912 / 1024, 256, 0, stream>>>(x, xb, 12582912);
  cvtk<<<1769472 / 1024, 256, 0, stream>>>(w_qkv, wqkvb, 1769472);
  cvtk<<<589824 / 1024, 256, 0, stream>>>(w_proj, wprojb, 589824);

  // QKV: 128 rowtiles x 18 coltiles = 2304 blocks (chunk 288)
  gemmk<0><<<2304, 256, 0, stream>>>(xb, wqkvb, b_qkv, qh, kh, vtb, nullptr, 768, 18, 288, 0);
  attnk<<<dim3(8, 192), 256, 0, stream>>>(qh, kh, vtb, ob, poly);
  // proj: 128 x 6 = 768 blocks (chunk 96), f32 out
  gemmk<1><<<768, 256, 0, stream>>>(ob, wprojb, b_proj, nullptr, nullptr, nullptr,
                                    (float*)d_out, 768, 6, 96, 768);
}

// Round 8
// 243.257 us; speedup vs baseline: 1.0293x; 1.0293x over previous
//
#include <hip/hip_runtime.h>
#include <hip/hip_bf16.h>

// PolyAttentionBlock: B=16 N=1024 C=768 H=12 D=64. attn = a*s^2+b*s+c (no softmax).
// cvt -> QK GEMM + V GEMM (128^2 BK=32, issue-early dbuf, k-major LDS) -> attn (dbuf) -> proj.

typedef float  f32x4  __attribute__((ext_vector_type(4)));
typedef __bf16 bf16x8 __attribute__((ext_vector_type(8)));
typedef __bf16 bf16x4 __attribute__((ext_vector_type(4)));

#define AS1 __attribute__((address_space(1)))
#define AS3 __attribute__((address_space(3)))

__device__ __forceinline__ void gl16(const void* g, void* l) {
  __builtin_amdgcn_global_load_lds((const AS1 unsigned int*)g, (AS3 unsigned int*)l, 16, 0, 0);
}

// ---------------- f32 -> bf16 cast ----------------
__global__ __launch_bounds__(256) void cvtk(const float* __restrict__ s,
                                            __bf16* __restrict__ d, int n) {
  int i = (blockIdx.x * 256 + threadIdx.x) * 4;
  if (i >= n) return;
  float4 v = *reinterpret_cast<const float4*>(s + i);
  bf16x4 o = { (__bf16)v.x, (__bf16)v.y, (__bf16)v.z, (__bf16)v.w };
  *reinterpret_cast<bf16x4*>(d + i) = o;
}

// ---------------- 128x128 BK=32 core, issue-early double-buffer ----------------
// 256 thr = 4 waves (2x2 of 64x64). LDS 32KB: buf b @ b*16384 (A 8KB chunks 0..7, B @ +8192).
// Chunk c (1KB) = rows c*16..+15, k-major [lg][l15][8elem] -> frag read = contiguous
// 1KB/wave (0 conflicts); staged by gl16 linear dest.
// Loop: STAGE(t+1 -> buf^1); READ(buf); MFMA; __syncthreads() (drain has full compute cover).
// acc[m][n][e]: SWAP -> C[row0+rw+m*16+l15][col0+cw+n*16+lg*4+e]  (e along cols)
//              !SWAP -> C[row0+rw+m*16+lg*4+e][col0+cw+n*16+l15]  (e along rows)
template <bool SWAP>
__device__ __forceinline__ void core32(const __bf16* __restrict__ A,
                                       const __bf16* __restrict__ W, int K,
                                       int row0, int col0, char* lds,
                                       int w, int l, f32x4 (&acc)[4][4]) {
  const int l15 = l & 15, lg = l >> 4;
  const int rw = (w >> 1) * 64, cw = (w & 1) * 64;
  // per-wave staging sources (chunks w and w+4 of each operand)
  const __bf16* a0 = A + (size_t)(row0 + w * 16 + l15) * K + lg * 8;
  const __bf16* a1 = A + (size_t)(row0 + (w + 4) * 16 + l15) * K + lg * 8;
  const __bf16* b0 = W + (size_t)(col0 + w * 16 + l15) * K + lg * 8;
  const __bf16* b1 = W + (size_t)(col0 + (w + 4) * 16 + l15) * K + lg * 8;
  char* dA0 = lds + w * 1024;
  char* dA1 = lds + (w + 4) * 1024;
  char* dB0 = lds + 8192 + w * 1024;
  char* dB1 = lds + 8192 + (w + 4) * 1024;

  gl16(a0, dA0); gl16(a1, dA1); gl16(b0, dB0); gl16(b1, dB1);
  __syncthreads();

  const int NT = K >> 5;
  for (int t = 0; t < NT; ++t) {
    const int cur = (t & 1) * 16384, nxt = 16384 - cur;
    if (t + 1 < NT) {
      const int ko = (t + 1) * 32;
      gl16(a0 + ko, dA0 + nxt); gl16(a1 + ko, dA1 + nxt);
      gl16(b0 + ko, dB0 + nxt); gl16(b1 + ko, dB1 + nxt);
    }
    bf16x8 af[4], bfr[4];
#pragma unroll
    for (int m = 0; m < 4; ++m)
      af[m] = *(const bf16x8*)(lds + cur + ((rw >> 4) + m) * 1024 + lg * 256 + l15 * 16);
#pragma unroll
    for (int n = 0; n < 4; ++n)
      bfr[n] = *(const bf16x8*)(lds + cur + 8192 + ((cw >> 4) + n) * 1024 + lg * 256 + l15 * 16);
    __builtin_amdgcn_s_setprio(1);
#pragma unroll
    for (int m = 0; m < 4; ++m)
#pragma unroll
      for (int n = 0; n < 4; ++n) {
        if (SWAP)
          acc[m][n] = __builtin_amdgcn_mfma_f32_16x16x32_bf16(bfr[n], af[m], acc[m][n], 0, 0, 0);
        else
          acc[m][n] = __builtin_amdgcn_mfma_f32_16x16x32_bf16(af[m], bfr[n], acc[m][n], 0, 0, 0);
      }
    __builtin_amdgcn_s_setprio(0);
    __syncthreads();  // drains vmcnt(0) (covered by READ+MFMA) + barrier
  }
}

__device__ __forceinline__ int xcd_swz(int fid, int chunk) {
  return (fid & 7) * chunk + (fid >> 3);
}

// ---- QK strips: cols 0..1535 of qkv -> qh/kh[bh][n][64] ----
__global__ __launch_bounds__(256, 4) void gemmQK(
    const __bf16* __restrict__ A, const __bf16* __restrict__ W,
    const float* __restrict__ bias, __bf16* __restrict__ qh,
    __bf16* __restrict__ kh) {
  __shared__ char lds[32768];
  const int t = threadIdx.x, w = t >> 6, l = t & 63;
  const int l15 = l & 15, lg = l >> 4;
  const int rw = (w >> 1) * 64, cw = (w & 1) * 64;
  const int logical = xcd_swz(blockIdx.x, 192);   // 1536 blocks, nby=12
  const int row0 = (logical / 12) * 128, col0 = (logical % 12) * 128;

  const f32x4 zz = {0.f, 0.f, 0.f, 0.f};
  f32x4 acc[4][4];
#pragma unroll
  for (int m = 0; m < 4; ++m)
#pragma unroll
    for (int n = 0; n < 4; ++n) acc[m][n] = zz;

  core32<true>(A, W, 768, row0, col0, lds, w, l, acc);

  f32x4 bv4[4];
#pragma unroll
  for (int n = 0; n < 4; ++n)
    bv4[n] = *(const f32x4*)(bias + col0 + cw + n * 16 + lg * 4);
#pragma unroll
  for (int m = 0; m < 4; ++m) {
    const int row = row0 + rw + m * 16 + l15;
    const int b = row >> 10, nn = row & 1023;
#pragma unroll
    for (int n = 0; n < 4; ++n) {
      const int colb = col0 + cw + n * 16 + lg * 4;
      bf16x4 pk;
#pragma unroll
      for (int e = 0; e < 4; ++e) pk[e] = (__bf16)(acc[m][n][e] + bv4[n][e]);
      if (colb < 768) {
        const int h = colb >> 6, d0 = colb & 63;
        *(bf16x4*)(qh + (((size_t)(b * 12 + h)) << 16) + nn * 64 + d0) = pk;
      } else {
        const int ck = colb - 768, h = ck >> 6, d0 = ck & 63;
        *(bf16x4*)(kh + (((size_t)(b * 12 + h)) << 16) + nn * 64 + d0) = pk;
      }
    }
  }
}

// ---- V strips: W rows 1536.. -> vT[bh][64][1024] ----
__global__ __launch_bounds__(256, 4) void gemmV(
    const __bf16* __restrict__ A, const __bf16* __restrict__ Wv,
    const float* __restrict__ biasv, __bf16* __restrict__ vt) {
  __shared__ char lds[32768];
  const int t = threadIdx.x, w = t >> 6, l = t & 63;
  const int l15 = l & 15, lg = l >> 4;
  const int rw = (w >> 1) * 64, cw = (w & 1) * 64;
  const int logical = xcd_swz(blockIdx.x, 96);    // 768 blocks, nby=6
  const int row0 = (logical / 6) * 128, col0 = (logical % 6) * 128;

  const f32x4 zz = {0.f, 0.f, 0.f, 0.f};
  f32x4 acc[4][4];
#pragma unroll
  for (int m = 0; m < 4; ++m)
#pragma unroll
    for (int n = 0; n < 4; ++n) acc[m][n] = zz;

  core32<false>(A, Wv, 768, row0, col0, lds, w, l, acc);

  float bv[4];
#pragma unroll
  for (int n = 0; n < 4; ++n) bv[n] = biasv[col0 + cw + n * 16 + l15];
#pragma unroll
  for (int m = 0; m < 4; ++m)
#pragma unroll
    for (int n = 0; n < 4; ++n) {
      const int cv = col0 + cw + n * 16 + l15;   // V col 0..767
      const int h = cv >> 6, d = cv & 63;
      const int row = row0 + rw + m * 16 + lg * 4;
      const int b = row >> 10, nn = row & 1023;
      bf16x4 pk;
#pragma unroll
      for (int e = 0; e < 4; ++e) pk[e] = (__bf16)(acc[m][n][e] + bv[n]);
      *(bf16x4*)(vt + (((size_t)(b * 12 + h)) << 16) + (d << 10) + nn) = pk;
    }
}

// ---- proj: f32 packed out ----
__global__ __launch_bounds__(256, 4) void gemmP(
    const __bf16* __restrict__ A, const __bf16* __restrict__ W,
    const float* __restrict__ bias, float* __restrict__ fout) {
  __shared__ char lds[32768];
  const int t = threadIdx.x, w = t >> 6, l = t & 63;
  const int l15 = l & 15, lg = l >> 4;
  const int rw = (w >> 1) * 64, cw = (w & 1) * 64;
  const int logical = xcd_swz(blockIdx.x, 96);    // 768 blocks, nby=6
  const int row0 = (logical / 6) * 128, col0 = (logical % 6) * 128;

  const f32x4 zz = {0.f, 0.f, 0.f, 0.f};
  f32x4 acc[4][4];
#pragma unroll
  for (int m = 0; m < 4; ++m)
#pragma unroll
    for (int n = 0; n < 4; ++n) acc[m][n] = zz;

  core32<true>(A, W, 768, row0, col0, lds, w, l, acc);

  f32x4 bv4[4];
#pragma unroll
  for (int n = 0; n < 4; ++n)
    bv4[n] = *(const f32x4*)(bias + col0 + cw + n * 16 + lg * 4);
#pragma unroll
  for (int m = 0; m < 4; ++m) {
    const int row = row0 + rw + m * 16 + l15;
#pragma unroll
    for (int n = 0; n < 4; ++n) {
      const int colb = col0 + cw + n * 16 + lg * 4;
      f32x4 v;
#pragma unroll
      for (int e = 0; e < 4; ++e) v[e] = acc[m][n][e] + bv4[n][e];
      *(f32x4*)(fout + (size_t)row * 768 + colb) = v;
    }
  }
}

// ---------------- fused poly attention (K/V issue-early dbuf, 1 barrier/tile) ----------------
// grid 1536 (XCD-chunked), 256 thr = 4 waves; KVBLK=64, 16 tiles.
// Swapped QK^T (S^T frags); swapped PV (O^T frags -> packed d-run stores).
__global__ __launch_bounds__(256, 3) void attnk(const __bf16* __restrict__ qh,
                                                const __bf16* __restrict__ kh,
                                                const __bf16* __restrict__ vT,
                                                __bf16* __restrict__ o,
                                                const float* __restrict__ poly) {
  __shared__ char lkv[2][16384];   // [buf]: K @ 0 ([m][d=64] swz), V @ 8192 ([d][m=64] swz)
  __shared__ __bf16 lP[128 * 64];  // [q][m=64]; wave w owns rows w*32..+31
  const int t = threadIdx.x, w = t >> 6, l = t & 63;
  const int l15 = l & 15, lg = l >> 4;

  const int fid = blockIdx.y * 8 + blockIdx.x;       // 0..1535
  const int logical = (fid & 7) * 192 + (fid >> 3);
  const int bh = logical >> 3, q0 = (logical & 7) * 128;
  const float pa = poly[0], pb = poly[1], pc = poly[2];
  const f32x4 zz = {0.f, 0.f, 0.f, 0.f};
  const size_t bhoff = ((size_t)bh) << 16;

  bf16x8 qf[2][2];
#pragma unroll
  for (int a = 0; a < 2; ++a)
#pragma unroll
    for (int kk = 0; kk < 2; ++kk)
      qf[a][kk] = *(const bf16x8*)(qh + bhoff + (q0 + w * 32 + 16 * a + l15) * 64 +
                                   kk * 32 + lg * 8);

  f32x4 oacc[2][4];
#pragma unroll
  for (int mf = 0; mf < 2; ++mf)
#pragma unroll
    for (int n = 0; n < 4; ++n) oacc[mf][n] = zz;

  const int srow = l >> 3;
  const int sunit = (l & 7) ^ (srow & 7);

#define STAGE(MT, BUF)                                                              \
  do {                                                                              \
    const int m0_ = (MT)*64;                                                        \
    _Pragma("unroll") for (int c = 0; c < 2; ++c) {                                 \
      const int s_ = w * 2 + c;                                                     \
      gl16(kh + bhoff + (m0_ + 8 * s_ + srow) * 64 + (sunit << 3),                  \
           lkv[BUF] + s_ * 1024);                                                   \
      gl16(vT + bhoff + (8 * s_ + srow) * 1024 + m0_ + (sunit << 3),                \
           lkv[BUF] + 8192 + s_ * 1024);                                            \
    }                                                                               \
  } while (0)

  STAGE(0, 0);
  __syncthreads();

  for (int mt = 0; mt < 16; ++mt) {
    const int cur = mt & 1;
    if (mt + 1 < 16) STAGE(mt + 1, cur ^ 1);

    // S^T = K Q^T
    f32x4 sacc[2][4];
#pragma unroll
    for (int kk = 0; kk < 2; ++kk) {
      bf16x8 kf[4];
#pragma unroll
      for (int c = 0; c < 4; ++c) {
        int r = 16 * c + l15;
        kf[c] = *(const bf16x8*)(lkv[cur] + r * 128 + (((kk * 4 + lg) ^ (r & 7)) << 4));
      }
      __builtin_amdgcn_s_setprio(1);
#pragma unroll
      for (int a = 0; a < 2; ++a)
#pragma unroll
        for (int c = 0; c < 4; ++c)
          sacc[a][c] = __builtin_amdgcn_mfma_f32_16x16x32_bf16(
              kf[c], qf[a][kk], kk == 0 ? zz : sacc[a][c], 0, 0, 0);
      __builtin_amdgcn_s_setprio(0);
    }

    // poly -> packed bf16x4 ds_write into own wave's lP rows
#pragma unroll
    for (int a = 0; a < 2; ++a)
#pragma unroll
      for (int c = 0; c < 4; ++c) {
        int q = w * 32 + 16 * a + l15;
        int mb2 = 32 * c + 8 * lg;
        bf16x4 pk;
#pragma unroll
        for (int e = 0; e < 4; ++e) {
          float s = sacc[a][c][e] * 0.125f;
          float p = (pa * s + pb) * s + pc;
          pk[e] = (__bf16)p;
        }
        *(bf16x4*)((char*)lP + q * 128 + (mb2 ^ ((q & 7) << 4))) = pk;
      }

    // O^T += V P^T (swapped: O^T frags, e runs along d)
#pragma unroll
    for (int kk = 0; kk < 2; ++kk) {
      bf16x8 vf[4];
#pragma unroll
      for (int nf = 0; nf < 4; ++nf) {
        int d = 16 * nf + l15;
        vf[nf] = *(const bf16x8*)(lkv[cur] + 8192 + d * 128 + (((kk * 4 + lg) ^ (d & 7)) << 4));
      }
      bf16x8 pf[2];
#pragma unroll
      for (int mf = 0; mf < 2; ++mf) {
        int q = w * 32 + 16 * mf + l15;
        pf[mf] = *(const bf16x8*)((const char*)lP + q * 128 + (((kk * 4 + lg) ^ (q & 7)) << 4));
      }
      __builtin_amdgcn_s_setprio(1);
#pragma unroll
      for (int mf = 0; mf < 2; ++mf)
#pragma unroll
        for (int nf = 0; nf < 4; ++nf)
          oacc[mf][nf] = __builtin_amdgcn_mfma_f32_16x16x32_bf16(vf[nf], pf[mf], oacc[mf][nf], 0, 0, 0);
      __builtin_amdgcn_s_setprio(0);
    }
    __syncthreads();  // buf[cur^1] staged+drained; lP reads done -> next tile safe
  }
#undef STAGE

  // epilogue: oacc[mf][nf][e] = O[q = q0+w*32+16mf+l15][d = 16nf+4lg+e] -> packed 8B stores
  const int b = bh / 12, h = bh - b * 12;
#pragma unroll
  for (int mf = 0; mf < 2; ++mf) {
    const int q = q0 + w * 32 + 16 * mf + l15;
#pragma unroll
    for (int nf = 0; nf < 4; ++nf) {
      bf16x4 pk;
#pragma unroll
      for (int e = 0; e < 4; ++e) pk[e] = (__bf16)oacc[mf][nf][e];
      *(bf16x4*)(o + (size_t)(b * 1024 + q) * 768 + h * 64 + 16 * nf + 4 * lg) = pk;
    }
  }
}

// ---------------- launch ----------------
extern "C" void kernel_launch(void* const* d_in, const int* in_sizes, int n_in,
                              void* d_out, int out_size, void* d_ws, size_t ws_size,
                              hipStream_t stream) {
  const float* x      = (const float*)d_in[0];
  const float* w_qkv  = (const float*)d_in[1];
  const float* b_qkv  = (const float*)d_in[2];
  const float* w_proj = (const float*)d_in[3];
  const float* b_proj = (const float*)d_in[4];
  const float* poly   = (const float*)d_in[5];

  char* ws = (char*)d_ws;
  __bf16* xb     = (__bf16*)(ws);                 // 16384x768   = 25165824 B
  __bf16* wqkvb  = (__bf16*)(ws + 25165824);      // 2304x768    =  3538944 B
  __bf16* wprojb = (__bf16*)(ws + 28704768);      // 768x768     =  1179648 B
  __bf16* qh     = (__bf16*)(ws + 29884416);      // 192x1024x64 = 25165824 B
  __bf16* kh     = (__bf16*)(ws + 55050240);      // 192x1024x64 = 25165824 B
  __bf16* vtb    = (__bf16*)(ws + 80216064);      // 192x64x1024 = 25165824 B
  __bf16* ob     = (__bf16*)(ws + 105381888);     // 16384x768   = 25165824 B

  cvtk<<<12582912 / 1024, 256, 0, stream>>>(x, xb, 12582912);
  cvtk<<<1769472 / 1024, 256, 0, stream>>>(w_qkv, wqkvb, 1769472);
  cvtk<<<589824 / 1024, 256, 0, stream>>>(w_proj, wprojb, 589824);

  gemmQK<<<1536, 256, 0, stream>>>(xb, wqkvb, b_qkv, qh, kh);
  gemmV<<<768, 256, 0, stream>>>(xb, wqkvb + (size_t)1536 * 768, b_qkv + 1536, vtb);
  attnk<<<dim3(8, 192), 256, 0, stream>>>(qh, kh, vtb, ob, poly);
  gemmP<<<768, 256, 0, stream>>>(ob, wprojb, b_proj, (float*)d_out);
}

// Round 9
// 237.912 us; speedup vs baseline: 1.0525x; 1.0225x over previous
//
#include <hip/hip_runtime.h>
#include <hip/hip_bf16.h>

// PolyAttentionBlock: B=16 N=1024 C=768 H=12 D=64. attn = a*s^2+b*s+c (no softmax).
// cvt -> QK/V GEMMs (128^2 BK=32, depth-3 counted-vmcnt pipeline) -> attn -> proj.

typedef float  f32x4  __attribute__((ext_vector_type(4)));
typedef __bf16 bf16x8 __attribute__((ext_vector_type(8)));
typedef __bf16 bf16x4 __attribute__((ext_vector_type(4)));

#define AS1 __attribute__((address_space(1)))
#define AS3 __attribute__((address_space(3)))

__device__ __forceinline__ void gl16(const void* g, void* l) {
  __builtin_amdgcn_global_load_lds((const AS1 unsigned int*)g, (AS3 unsigned int*)l, 16, 0, 0);
}

// ---------------- f32 -> bf16 cast ----------------
__global__ __launch_bounds__(256) void cvtk(const float* __restrict__ s,
                                            __bf16* __restrict__ d, int n) {
  int i = (blockIdx.x * 256 + threadIdx.x) * 4;
  if (i >= n) return;
  float4 v = *reinterpret_cast<const float4*>(s + i);
  bf16x4 o = { (__bf16)v.x, (__bf16)v.y, (__bf16)v.z, (__bf16)v.w };
  *reinterpret_cast<bf16x4*>(d + i) = o;
}

// ---------------- 128x128 BK=32 core, depth-3 counted-vmcnt pipeline ----------------
// 256 thr = 4 waves (2x2 of 64x64). LDS 48KB = 3 bufs x (A 8KB + B 8KB), k-major 1KB
// chunks (conflict-free contiguous ds_read_b128). K=768 fixed -> 24 tiles.
// Pipeline: stage t0..t2; iter t: vmcnt(8) [t's 4 loads done, t+1/t+2 in flight],
// barrier, read+MFMA, barrier, stage t+3 -> same buf. Tail gates 8/4/0. Loads NEVER
// drain to 0 in steady state (T4, m218). Race-free: gate-before-barrier => all waves'
// tile-t writes landed; restage only after barrier2 which follows all reads (MFMA dep).
// acc[m][n][e]: SWAP -> C[row0+rw+m*16+l15][col0+cw+n*16+lg*4+e]  (e along cols)
//              !SWAP -> C[row0+rw+m*16+lg*4+e][col0+cw+n*16+l15]  (e along rows)
template <bool SWAP>
__device__ __forceinline__ void core_d3(const __bf16* __restrict__ A,
                                        const __bf16* __restrict__ W,
                                        int row0, int col0, char* lds,
                                        int w, int l, f32x4 (&acc)[4][4]) {
  const int K = 768;
  const int l15 = l & 15, lg = l >> 4;
  const int rw = (w >> 1) * 64, cw = (w & 1) * 64;
  // per-wave staging: chunks w and w+4 of A and B (each 1KB = 16 rows x 32k k-major)
  const __bf16* a0 = A + (size_t)(row0 + w * 16 + l15) * K + lg * 8;
  const __bf16* a1 = a0 + (size_t)64 * K;
  const __bf16* b0 = W + (size_t)(col0 + w * 16 + l15) * K + lg * 8;
  const __bf16* b1 = b0 + (size_t)64 * K;
  char* dA0 = lds + w * 1024;
  char* dA1 = dA0 + 4096;
  char* dB0 = lds + 8192 + w * 1024;
  char* dB1 = dB0 + 4096;

#define STG(BUF, T)                                                        \
  do {                                                                     \
    const int ko_ = (T)*32;                                                \
    gl16(a0 + ko_, dA0 + (BUF)*16384); gl16(a1 + ko_, dA1 + (BUF)*16384);  \
    gl16(b0 + ko_, dB0 + (BUF)*16384); gl16(b1 + ko_, dB1 + (BUF)*16384);  \
  } while (0)
#define COMP(BUF)                                                               \
  do {                                                                          \
    bf16x8 af[4], bfr[4];                                                       \
    _Pragma("unroll") for (int m = 0; m < 4; ++m)                               \
        af[m] = *(const bf16x8*)(lds + (BUF)*16384 + ((rw >> 4) + m) * 1024 +   \
                                 lg * 256 + l15 * 16);                          \
    _Pragma("unroll") for (int n = 0; n < 4; ++n)                               \
        bfr[n] = *(const bf16x8*)(lds + (BUF)*16384 + 8192 +                    \
                                  ((cw >> 4) + n) * 1024 + lg * 256 + l15 * 16);\
    __builtin_amdgcn_s_setprio(1);                                              \
    _Pragma("unroll") for (int m = 0; m < 4; ++m)                               \
        _Pragma("unroll") for (int n = 0; n < 4; ++n) {                         \
      if (SWAP)                                                                 \
        acc[m][n] = __builtin_amdgcn_mfma_f32_16x16x32_bf16(bfr[n], af[m],      \
                                                            acc[m][n], 0, 0, 0);\
      else                                                                      \
        acc[m][n] = __builtin_amdgcn_mfma_f32_16x16x32_bf16(af[m], bfr[n],      \
                                                            acc[m][n], 0, 0, 0);\
    }                                                                           \
    __builtin_amdgcn_s_setprio(0);                                              \
  } while (0)
#define GATE8 asm volatile("s_waitcnt vmcnt(8)" ::: "memory")
#define GATE4 asm volatile("s_waitcnt vmcnt(4)" ::: "memory")
#define GATE0 asm volatile("s_waitcnt vmcnt(0)" ::: "memory")
#define BARR __builtin_amdgcn_s_barrier()

  STG(0, 0); STG(1, 1); STG(2, 2);
  for (int j = 0; j < 7; ++j) {
    const int T = 3 * j;
    GATE8; BARR; COMP(0); BARR; STG(0, T + 3);
    GATE8; BARR; COMP(1); BARR; STG(1, T + 4);
    GATE8; BARR; COMP(2); BARR; STG(2, T + 5);
  }
  GATE8; BARR; COMP(0); BARR;   // tile 21
  GATE4; BARR; COMP(1); BARR;   // tile 22
  GATE0; BARR; COMP(2);         // tile 23
#undef STG
#undef COMP
#undef GATE8
#undef GATE4
#undef GATE0
#undef BARR
}

__device__ __forceinline__ int xcd_swz(int fid, int chunk) {
  return (fid & 7) * chunk + (fid >> 3);
}

// ---- QK strips: cols 0..1535 of qkv -> qh/kh[bh][n][64] ----
__global__ __launch_bounds__(256, 3) void gemmQK(
    const __bf16* __restrict__ A, const __bf16* __restrict__ W,
    const float* __restrict__ bias, __bf16* __restrict__ qh,
    __bf16* __restrict__ kh) {
  __shared__ char lds[49152];
  const int t = threadIdx.x, w = t >> 6, l = t & 63;
  const int l15 = l & 15, lg = l >> 4;
  const int rw = (w >> 1) * 64, cw = (w & 1) * 64;
  const int logical = xcd_swz(blockIdx.x, 192);   // 1536 blocks, nby=12
  const int row0 = (logical / 12) * 128, col0 = (logical % 12) * 128;

  const f32x4 zz = {0.f, 0.f, 0.f, 0.f};
  f32x4 acc[4][4];
#pragma unroll
  for (int m = 0; m < 4; ++m)
#pragma unroll
    for (int n = 0; n < 4; ++n) acc[m][n] = zz;

  core_d3<true>(A, W, row0, col0, lds, w, l, acc);

  f32x4 bv4[4];
#pragma unroll
  for (int n = 0; n < 4; ++n)
    bv4[n] = *(const f32x4*)(bias + col0 + cw + n * 16 + lg * 4);
#pragma unroll
  for (int m = 0; m < 4; ++m) {
    const int row = row0 + rw + m * 16 + l15;
    const int b = row >> 10, nn = row & 1023;
#pragma unroll
    for (int n = 0; n < 4; ++n) {
      const int colb = col0 + cw + n * 16 + lg * 4;
      bf16x4 pk;
#pragma unroll
      for (int e = 0; e < 4; ++e) pk[e] = (__bf16)(acc[m][n][e] + bv4[n][e]);
      if (colb < 768) {
        const int h = colb >> 6, d0 = colb & 63;
        *(bf16x4*)(qh + (((size_t)(b * 12 + h)) << 16) + nn * 64 + d0) = pk;
      } else {
        const int ck = colb - 768, h = ck >> 6, d0 = ck & 63;
        *(bf16x4*)(kh + (((size_t)(b * 12 + h)) << 16) + nn * 64 + d0) = pk;
      }
    }
  }
}

// ---- V strips: W rows 1536.. -> vT[bh][64][1024] ----
__global__ __launch_bounds__(256, 3) void gemmV(
    const __bf16* __restrict__ A, const __bf16* __restrict__ Wv,
    const float* __restrict__ biasv, __bf16* __restrict__ vt) {
  __shared__ char lds[49152];
  const int t = threadIdx.x, w = t >> 6, l = t & 63;
  const int l15 = l & 15, lg = l >> 4;
  const int rw = (w >> 1) * 64, cw = (w & 1) * 64;
  const int logical = xcd_swz(blockIdx.x, 96);    // 768 blocks, nby=6
  const int row0 = (logical / 6) * 128, col0 = (logical % 6) * 128;

  const f32x4 zz = {0.f, 0.f, 0.f, 0.f};
  f32x4 acc[4][4];
#pragma unroll
  for (int m = 0; m < 4; ++m)
#pragma unroll
    for (int n = 0; n < 4; ++n) acc[m][n] = zz;

  core_d3<false>(A, Wv, row0, col0, lds, w, l, acc);

  float bv[4];
#pragma unroll
  for (int n = 0; n < 4; ++n) bv[n] = biasv[col0 + cw + n * 16 + l15];
#pragma unroll
  for (int m = 0; m < 4; ++m)
#pragma unroll
    for (int n = 0; n < 4; ++n) {
      const int cv = col0 + cw + n * 16 + l15;   // V col 0..767
      const int h = cv >> 6, d = cv & 63;
      const int row = row0 + rw + m * 16 + lg * 4;
      const int b = row >> 10, nn = row & 1023;
      bf16x4 pk;
#pragma unroll
      for (int e = 0; e < 4; ++e) pk[e] = (__bf16)(acc[m][n][e] + bv[n]);
      *(bf16x4*)(vt + (((size_t)(b * 12 + h)) << 16) + (d << 10) + nn) = pk;
    }
}

// ---- proj: f32 packed out ----
__global__ __launch_bounds__(256, 3) void gemmP(
    const __bf16* __restrict__ A, const __bf16* __restrict__ W,
    const float* __restrict__ bias, float* __restrict__ fout) {
  __shared__ char lds[49152];
  const int t = threadIdx.x, w = t >> 6, l = t & 63;
  const int l15 = l & 15, lg = l >> 4;
  const int rw = (w >> 1) * 64, cw = (w & 1) * 64;
  const int logical = xcd_swz(blockIdx.x, 96);    // 768 blocks, nby=6
  const int row0 = (logical / 6) * 128, col0 = (logical % 6) * 128;

  const f32x4 zz = {0.f, 0.f, 0.f, 0.f};
  f32x4 acc[4][4];
#pragma unroll
  for (int m = 0; m < 4; ++m)
#pragma unroll
    for (int n = 0; n < 4; ++n) acc[m][n] = zz;

  core_d3<true>(A, W, row0, col0, lds, w, l, acc);

  f32x4 bv4[4];
#pragma unroll
  for (int n = 0; n < 4; ++n)
    bv4[n] = *(const f32x4*)(bias + col0 + cw + n * 16 + lg * 4);
#pragma unroll
  for (int m = 0; m < 4; ++m) {
    const int row = row0 + rw + m * 16 + l15;
#pragma unroll
    for (int n = 0; n < 4; ++n) {
      const int colb = col0 + cw + n * 16 + lg * 4;
      f32x4 v;
#pragma unroll
      for (int e = 0; e < 4; ++e) v[e] = acc[m][n][e] + bv4[n][e];
      *(f32x4*)(fout + (size_t)row * 768 + colb) = v;
    }
  }
}

// ---------------- fused poly attention (unchanged from r8) ----------------
__global__ __launch_bounds__(256, 3) void attnk(const __bf16* __restrict__ qh,
                                                const __bf16* __restrict__ kh,
                                                const __bf16* __restrict__ vT,
                                                __bf16* __restrict__ o,
                                                const float* __restrict__ poly) {
  __shared__ char lkv[2][16384];   // [buf]: K @ 0 ([m][d=64] swz), V @ 8192 ([d][m=64] swz)
  __shared__ __bf16 lP[128 * 64];  // [q][m=64]; wave w owns rows w*32..+31
  const int t = threadIdx.x, w = t >> 6, l = t & 63;
  const int l15 = l & 15, lg = l >> 4;

  const int fid = blockIdx.y * 8 + blockIdx.x;       // 0..1535
  const int logical = (fid & 7) * 192 + (fid >> 3);
  const int bh = logical >> 3, q0 = (logical & 7) * 128;
  const float pa = poly[0], pb = poly[1], pc = poly[2];
  const f32x4 zz = {0.f, 0.f, 0.f, 0.f};
  const size_t bhoff = ((size_t)bh) << 16;

  bf16x8 qf[2][2];
#pragma unroll
  for (int a = 0; a < 2; ++a)
#pragma unroll
    for (int kk = 0; kk < 2; ++kk)
      qf[a][kk] = *(const bf16x8*)(qh + bhoff + (q0 + w * 32 + 16 * a + l15) * 64 +
                                   kk * 32 + lg * 8);

  f32x4 oacc[2][4];
#pragma unroll
  for (int mf = 0; mf < 2; ++mf)
#pragma unroll
    for (int n = 0; n < 4; ++n) oacc[mf][n] = zz;

  const int srow = l >> 3;
  const int sunit = (l & 7) ^ (srow & 7);

#define STAGE(MT, BUF)                                                              \
  do {                                                                              \
    const int m0_ = (MT)*64;                                                        \
    _Pragma("unroll") for (int c = 0; c < 2; ++c) {                                 \
      const int s_ = w * 2 + c;                                                     \
      gl16(kh + bhoff + (m0_ + 8 * s_ + srow) * 64 + (sunit << 3),                  \
           lkv[BUF] + s_ * 1024);                                                   \
      gl16(vT + bhoff + (8 * s_ + srow) * 1024 + m0_ + (sunit << 3),                \
           lkv[BUF] + 8192 + s_ * 1024);                                            \
    }                                                                               \
  } while (0)

  STAGE(0, 0);
  __syncthreads();

  for (int mt = 0; mt < 16; ++mt) {
    const int cur = mt & 1;
    if (mt + 1 < 16) STAGE(mt + 1, cur ^ 1);

    // S^T = K Q^T
    f32x4 sacc[2][4];
#pragma unroll
    for (int kk = 0; kk < 2; ++kk) {
      bf16x8 kf[4];
#pragma unroll
      for (int c = 0; c < 4; ++c) {
        int r = 16 * c + l15;
        kf[c] = *(const bf16x8*)(lkv[cur] + r * 128 + (((kk * 4 + lg) ^ (r & 7)) << 4));
      }
      __builtin_amdgcn_s_setprio(1);
#pragma unroll
      for (int a = 0; a < 2; ++a)
#pragma unroll
        for (int c = 0; c < 4; ++c)
          sacc[a][c] = __builtin_amdgcn_mfma_f32_16x16x32_bf16(
              kf[c], qf[a][kk], kk == 0 ? zz : sacc[a][c], 0, 0, 0);
      __builtin_amdgcn_s_setprio(0);
    }

    // poly -> packed bf16x4 ds_write into own wave's lP rows
#pragma unroll
    for (int a = 0; a < 2; ++a)
#pragma unroll
      for (int c = 0; c < 4; ++c) {
        int q = w * 32 + 16 * a + l15;
        int mb2 = 32 * c + 8 * lg;
        bf16x4 pk;
#pragma unroll
        for (int e = 0; e < 4; ++e) {
          float s = sacc[a][c][e] * 0.125f;
          float p = (pa * s + pb) * s + pc;
          pk[e] = (__bf16)p;
        }
        *(bf16x4*)((char*)lP + q * 128 + (mb2 ^ ((q & 7) << 4))) = pk;
      }

    // O^T += V P^T (swapped: O^T frags, e runs along d)
#pragma unroll
    for (int kk = 0; kk < 2; ++kk) {
      bf16x8 vf[4];
#pragma unroll
      for (int nf = 0; nf < 4; ++nf) {
        int d = 16 * nf + l15;
        vf[nf] = *(const bf16x8*)(lkv[cur] + 8192 + d * 128 + (((kk * 4 + lg) ^ (d & 7)) << 4));
      }
      bf16x8 pf[2];
#pragma unroll
      for (int mf = 0; mf < 2; ++mf) {
        int q = w * 32 + 16 * mf + l15;
        pf[mf] = *(const bf16x8*)((const char*)lP + q * 128 + (((kk * 4 + lg) ^ (q & 7)) << 4));
      }
      __builtin_amdgcn_s_setprio(1);
#pragma unroll
      for (int mf = 0; mf < 2; ++mf)
#pragma unroll
        for (int nf = 0; nf < 4; ++nf)
          oacc[mf][nf] = __builtin_amdgcn_mfma_f32_16x16x32_bf16(vf[nf], pf[mf], oacc[mf][nf], 0, 0, 0);
      __builtin_amdgcn_s_setprio(0);
    }
    __syncthreads();
  }
#undef STAGE

  const int b = bh / 12, h = bh - b * 12;
#pragma unroll
  for (int mf = 0; mf < 2; ++mf) {
    const int q = q0 + w * 32 + 16 * mf + l15;
#pragma unroll
    for (int nf = 0; nf < 4; ++nf) {
      bf16x4 pk;
#pragma unroll
      for (int e = 0; e < 4; ++e) pk[e] = (__bf16)oacc[mf][nf][e];
      *(bf16x4*)(o + (size_t)(b * 1024 + q) * 768 + h * 64 + 16 * nf + 4 * lg) = pk;
    }
  }
}

// ---------------- launch ----------------
extern "C" void kernel_launch(void* const* d_in, const int* in_sizes, int n_in,
                              void* d_out, int out_size, void* d_ws, size_t ws_size,
                              hipStream_t stream) {
  const float* x      = (const float*)d_in[0];
  const float* w_qkv  = (const float*)d_in[1];
  const float* b_qkv  = (const float*)d_in[2];
  const float* w_proj = (const float*)d_in[3];
  const float* b_proj = (const float*)d_in[4];
  const float* poly   = (const float*)d_in[5];

  char* ws = (char*)d_ws;
  __bf16* xb     = (__bf16*)(ws);                 // 16384x768   = 25165824 B
  __bf16* wqkvb  = (__bf16*)(ws + 25165824);      // 2304x768    =  3538944 B
  __bf16* wprojb = (__bf16*)(ws + 28704768);      // 768x768     =  1179648 B
  __bf16* qh     = (__bf16*)(ws + 29884416);      // 192x1024x64 = 25165824 B
  __bf16* kh     = (__bf16*)(ws + 55050240);      // 192x1024x64 = 25165824 B
  __bf16* vtb    = (__bf16*)(ws + 80216064);      // 192x64x1024 = 25165824 B
  __bf16* ob     = (__bf16*)(ws + 105381888);     // 16384x768   = 25165824 B

  cvtk<<<12582912 / 1024, 256, 0, stream>>>(x, xb, 12582912);
  cvtk<<<1769472 / 1024, 256, 0, stream>>>(w_qkv, wqkvb, 1769472);
  cvtk<<<589824 / 1024, 256, 0, stream>>>(w_proj, wprojb, 589824);

  gemmQK<<<1536, 256, 0, stream>>>(xb, wqkvb, b_qkv, qh, kh);
  gemmV<<<768, 256, 0, stream>>>(xb, wqkvb + (size_t)1536 * 768, b_qkv + 1536, vtb);
  attnk<<<dim3(8, 192), 256, 0, stream>>>(qh, kh, vtb, ob, poly);
  gemmP<<<768, 256, 0, stream>>>(ob, wprojb, b_proj, (float*)d_out);
}